// Round 15
// baseline (325.554 us; speedup 1.0000x reference)
//
#include <hip/hip_runtime.h>
#include <hip/hip_bf16.h>

#define SPIX 1000
#define NCLS 21
#define PP (512*512)          // pixels per image, 2^18
#define NB_IMG 8
#define EPB (NCLS*PP)         // elements per batch in pred (= 21*2^18 f-values)

// scatter geometry: contiguous 32768-wide f-window per block; 2^15 | 2^18 so
// the class row c = f>>18 is CONSTANT within a block.
#define FWIN 32768
#define BLKS_PER_B (EPB / FWIN)   // 168
#define DUMP 1000                 // garbage accumulator slot (rows sized 1024)

// ws layout (floats)
#define R_OFF   0                      // [8][21][1000]
#define TR_OFF  (NB_IMG*NCLS*SPIX)     // [8]
#define NS_OFF  (TR_OFF + NB_IMG)      // [1] norm^2
#define CNT_OFF (NS_OFF + 1)           // [1] valid count
#define CTR_OFF (CNT_OFF + 1)          // [1] trace-block completion counter
#define WS_FLOATS (CTR_OFF + 1)

__device__ __forceinline__ void fatomic_add(float* p, float v) {
    unsafeAtomicAdd(p, v);   // native ds_add_f32 / global_atomic_add_f32
}

#define CLOBBER() asm volatile("" ::: "memory")

// Scatter + (on blockIdx.y==8) the ||W||^2 and valid-count reductions.
// R12 protocol (per-phase clobbers, batched lgkm waits). Single change vs R12:
// claim LOSERS fall back to GLOBAL atomics (L2 atomic units, fire-and-forget)
// instead of ds_add — the lane-serial LDS atomic unit was ~40% of DS-pipe
// usage for 13% of elements. Both paths atomic-add into the final sum, so
// winner/loser ordering constraints vanish.
__global__ __launch_bounds__(512, 8) void scatter_kernel(const float* __restrict__ pred,
                                                         const int* __restrict__ seg,
                                                         const float* __restrict__ W,
                                                         float* __restrict__ Rout,
                                                         float* __restrict__ ns,
                                                         float* __restrict__ cnt) {
    if (blockIdx.y == NB_IMG) {            // -------- scalars blocks --------
        if (blockIdx.x < 128) {
            const float4* W4 = (const float4*)W;
            const int n4 = (NB_IMG * SPIX * SPIX) / 4;
            float s = 0.f;
            for (int i = blockIdx.x * 512 + threadIdx.x; i < n4; i += 128 * 512) {
                float4 v = W4[i];
                s += v.x*v.x + v.y*v.y + v.z*v.z + v.w*v.w;
            }
            #pragma unroll
            for (int off = 32; off; off >>= 1) s += __shfl_xor(s, off);
            if ((threadIdx.x & 63) == 0) fatomic_add(ns, s);
        } else {
            const int4* s4 = (const int4*)seg;
            const int n4 = (NB_IMG * PP) / 4;
            int c = 0;
            for (int i = (blockIdx.x - 128) * 512 + threadIdx.x; i < n4; i += 40 * 512) {
                int4 v = s4[i];
                c += ((unsigned)v.x < SPIX) + ((unsigned)v.y < SPIX) + ((unsigned)v.z < SPIX) + ((unsigned)v.w < SPIX);
            }
            float f = (float)c;
            #pragma unroll
            for (int off = 32; off; off >>= 1) f += __shfl_xor(f, off);
            if ((threadIdx.x & 63) == 0) fatomic_add(cnt, f);
        }
        return;
    }
    // -------- scatter blocks --------
    __shared__ float          Rw[8][1024];   // wave-private accumulators, 32 KB
    __shared__ unsigned short Mk[8][1024];   // wave-private claim markers, 16 KB
    const int b    = blockIdx.y;
    const int tid  = threadIdx.x;
    const int wave = tid >> 6;
    const unsigned short lane = (unsigned short)(tid & 63);
    const unsigned f0 = (unsigned)blockIdx.x * FWIN;
    const unsigned c0 = f0 >> 18;            // constant class row for this block
    const unsigned p0 = f0 & (PP - 1);       // window start pixel (never wraps)

    for (int i = tid; i < 8 * 1024; i += 512) ((float*)Rw)[i] = 0.f;
    __syncthreads();

    float*          wR = Rw[wave];
    unsigned short* wM = Mk[wave];

    const float* pb   = pred + (size_t)b * EPB;
    const int*   segb = seg + (size_t)b * PP + p0;
    float* Rbrow = Rout + (size_t)b * NCLS * SPIX + (size_t)c0 * SPIX;

    // issue-next-iteration loads (seg int4 + 4 pred gathers)
#define PREF(E0, SV, VV) do {                                     \
        SV = *(const int4*)(segb + (E0));                         \
        unsigned fk = f0 + (unsigned)(E0);                        \
        unsigned sp = fk / 21u;                                   \
        unsigned ch = fk - sp * 21u;                              \
        _Pragma("unroll")                                         \
        for (int k = 0; k < 4; ++k) {                             \
            VV[k] = pb[(ch << 18) + sp];                          \
            ch++;                                                 \
            bool c21 = (ch == 21u);                               \
            sp += c21 ? 1u : 0u;                                  \
            ch  = c21 ? 0u : ch;                                  \
        }                                                         \
    } while (0)

    int4 svN; float vN[4];
    PREF(tid * 4, svN, vN);                                  // prologue: it=0

    for (int it = 0; it < FWIN / (512 * 4); ++it) {          // 16 iterations
        int4 sv = svN;
        float vA[4] = {vN[0], vN[1], vN[2], vN[3]};
        if (it + 1 < FWIN / (512 * 4)) {
            PREF(((it + 1) * 512 + tid) * 4, svN, vN);       // in flight during protocol
        }
        int sA[4];
        #pragma unroll
        for (int k = 0; k < 4; ++k) {
            int s = (&sv.x)[k];
            sA[k] = ((unsigned)s < SPIX) ? s : DUMP;
        }
        // lane-local dedup: merge equal bins so a lane wins a bin at most once
        #pragma unroll
        for (int i = 0; i < 3; ++i)
            #pragma unroll
            for (int j = i + 1; j < 4; ++j) {
                bool e = (sA[j] == sA[i]) && (sA[i] != DUMP);
                vA[i] += e ? vA[j] : 0.f;
                sA[j]  = e ? DUMP  : sA[j];
            }
        // phase 1: claims (4 ds_write_b16, batched waits)
        #pragma unroll
        for (int k = 0; k < 4; ++k) wM[sA[k]] = lane;
        CLOBBER();
        // phase 2: claim readback (4 ds_read_u16)
        unsigned short rd[4];
        #pragma unroll
        for (int k = 0; k < 4; ++k) rd[k] = wM[sA[k]];
        CLOBBER();
        // phase 3: RMW reads (unconditional; losers read harmlessly)
        float od[4];
        #pragma unroll
        for (int k = 0; k < 4; ++k) od[k] = wR[sA[k]];
        CLOBBER();
        // phase 4: winner writes, branchless (losers write garbage to DUMP)
        bool lose1[4];
        #pragma unroll
        for (int k = 0; k < 4; ++k) {
            lose1[k] = (rd[k] != lane);
            wR[lose1[k] ? DUMP : sA[k]] = od[k] + vA[k];
        }
        // phase 5: losers -> L2 global atomics (fire-and-forget, off the DS pipe)
        #pragma unroll
        for (int k = 0; k < 4; ++k) {
            if (lose1[k] && sA[k] != DUMP) fatomic_add(&Rbrow[sA[k]], vA[k]);
        }
    }
#undef PREF
    __syncthreads();

    // merge 8 wave copies, one global atomic per bin
    for (int i = tid; i < SPIX; i += 512) {
        float a = 0.f;
        #pragma unroll
        for (int w = 0; w < 8; ++w) a += Rw[w][i];
        if (a != 0.f) fatomic_add(&Rbrow[i], a);
    }
}

// trace[b] = sum_{s,t} L[b,s,t] * sum_c R[b,c,s]*R[b,c,t]; last block finalizes.
__global__ __launch_bounds__(512) void trace_kernel(const float* __restrict__ L,
                                                    const float* __restrict__ R,
                                                    float* __restrict__ traces,
                                                    const float* __restrict__ ns,
                                                    const float* __restrict__ cnt,
                                                    unsigned* __restrict__ ctr,
                                                    float* __restrict__ out) {
    __shared__ float Rl[NCLS * SPIX];   // 84 KB
    const int b = blockIdx.y;
    const float* Rb = R + (size_t)b * NCLS * SPIX;
    for (int i = threadIdx.x; i < NCLS * SPIX; i += 512) Rl[i] = Rb[i];
    __syncthreads();

    const int wave = threadIdx.x >> 6;
    const int lane = threadIdx.x & 63;
    const float* Lb = L + (size_t)b * SPIX * SPIX;

    const int s0 = (blockIdx.x * 8 + wave) * 4;   // 32 blocks * 8 waves * 4 rows = 1024
    bool val[4];
    const float4* Lr[4];
    #pragma unroll
    for (int r = 0; r < 4; ++r) {
        int sr = s0 + r;
        val[r] = sr < SPIX;
        Lr[r] = (const float4*)(Lb + (size_t)(val[r] ? sr : (SPIX - 1)) * SPIX);
    }

    float acc[4][NCLS];
    #pragma unroll
    for (int r = 0; r < 4; ++r)
        #pragma unroll
        for (int c = 0; c < NCLS; ++c) acc[r][c] = 0.f;

    #pragma unroll
    for (int it = 0; it < 4; ++it) {
        int idx = it * 64 + lane;          // float4 index within row, 0..249
        if (idx < SPIX / 4) {
            float4 l[4];
            #pragma unroll
            for (int r = 0; r < 4; ++r)
                l[r] = val[r] ? Lr[r][idx] : make_float4(0.f, 0.f, 0.f, 0.f);
            #pragma unroll
            for (int c = 0; c < NCLS; ++c) {
                float4 rr = *(const float4*)&Rl[c * SPIX + idx * 4];
                #pragma unroll
                for (int r = 0; r < 4; ++r)
                    acc[r][c] += l[r].x * rr.x + l[r].y * rr.y + l[r].z * rr.z + l[r].w * rr.w;
            }
        }
    }

    float partial = 0.f;
    #pragma unroll
    for (int c = 0; c < NCLS; ++c)
        #pragma unroll
        for (int r = 0; r < 4; ++r)
            if (val[r]) partial += Rl[c * SPIX + s0 + r] * acc[r][c];

    #pragma unroll
    for (int off = 32; off; off >>= 1) partial += __shfl_xor(partial, off);
    if (lane == 0) fatomic_add(&traces[b], partial);

    __syncthreads();
    if (threadIdx.x == 0) {
        __threadfence();
        unsigned old = atomicAdd(ctr, 1u);
        if (old == 32u * NB_IMG - 1u) {    // last block finalizes
            __threadfence();
            float t = 0.f;
            #pragma unroll
            for (int i = 0; i < NB_IMG; ++i)
                t += __hip_atomic_load(&traces[i], __ATOMIC_RELAXED, __HIP_MEMORY_SCOPE_AGENT);
            float denom = cnt[0] + 1e-16f;
            out[0] = (2.f / sqrtf(ns[0])) * t / (denom * denom) / (float)NB_IMG;
        }
    }
}

extern "C" void kernel_launch(void* const* d_in, const int* in_sizes, int n_in,
                              void* d_out, int out_size, void* d_ws, size_t ws_size,
                              hipStream_t stream) {
    const float* pred = (const float*)d_in[0];
    const float* Wc   = (const float*)d_in[1];
    const float* Lc   = (const float*)d_in[2];
    const int*   seg  = (const int*)d_in[3];
    float* ws = (float*)d_ws;
    float* out = (float*)d_out;

    hipMemsetAsync(d_ws, 0, WS_FLOATS * sizeof(float), stream);

    scatter_kernel<<<dim3(BLKS_PER_B, NB_IMG + 1), 512, 0, stream>>>(
        pred, seg, Wc, ws + R_OFF, ws + NS_OFF, ws + CNT_OFF);

    trace_kernel<<<dim3(32, NB_IMG), 512, 0, stream>>>(
        Lc, ws + R_OFF, ws + TR_OFF, ws + NS_OFF, ws + CNT_OFF,
        (unsigned*)(ws + CTR_OFF), out);
}

// Round 17
// 275.770 us; speedup vs baseline: 1.1805x; 1.1805x over previous
//
#include <hip/hip_runtime.h>
#include <hip/hip_bf16.h>

#define SPIX 1000
#define NCLS 21
#define PP (512*512)          // pixels per image, 2^18
#define NB_IMG 8
#define EPB (NCLS*PP)         // elements per batch in pred (= 21*2^18 f-values)

// scatter geometry: contiguous 32768-wide f-window per block; 2^15 | 2^18 so
// the class row c = f>>18 is CONSTANT within a block.
#define FWIN 32768
#define BLKS_PER_B (EPB / FWIN)   // 168
#define DUMP 1000                 // garbage accumulator slot (rows sized 1024)

#define NSCAT (BLKS_PER_B * NB_IMG)   // 1344
#define NSCAL 168
#define TXB 63                        // trace x-blocks: 63*8waves*2rows = 1008 >= 1000
#define NTRC (TXB * NB_IMG)           // 504
#define NBLKS (NSCAT + NSCAL + NTRC)  // 2016

// ws layout (floats)
#define R_OFF   0                      // [8][21][1000]
#define TR_OFF  (NB_IMG*NCLS*SPIX)     // [8] traces
#define NS_OFF  (TR_OFF + NB_IMG)      // [1] norm^2
#define CNT_OFF (NS_OFF + 1)           // [1] valid count
#define DONE_OFF (CNT_OFF + 1)         // [8] per-batch scatter completion (u32)
#define SD_OFF  (DONE_OFF + NB_IMG)    // [1] scalars completion (u32)
#define CT_OFF  (SD_OFF + 1)           // [1] trace completion (u32)
#define WS_FLOATS (CT_OFF + 1)

__device__ __forceinline__ void fatomic_add(float* p, float v) {
    unsafeAtomicAdd(p, v);   // native ds_add_f32 / global_atomic_add_f32
}

#define CLOBBER() asm volatile("" ::: "memory")

// One fused kernel. Blocks [0,1344): scatter (R12 protocol, unchanged).
// [1344,1512): scalars. [1512,2016): trace, spin-waiting on per-batch done
// counters so trace(b) overlaps scatter(b'>b). Trace reads R from global
// (L1/L2-resident) so the kernel's static LDS stays 48 KB (3 blocks/CU).
__global__ __launch_bounds__(512, 4) void fused_kernel(const float* __restrict__ pred,
                                                       const int* __restrict__ seg,
                                                       const float* __restrict__ W,
                                                       const float* __restrict__ L,
                                                       float* __restrict__ ws,
                                                       float* __restrict__ out) {
    __shared__ float          Rw[8][1024];   // scatter: wave-private accumulators, 32 KB
    __shared__ unsigned short Mk[8][1024];   // scatter: wave-private claim markers, 16 KB

    float* Rbase   = ws + R_OFF;
    float* traces  = ws + TR_OFF;
    float* ns      = ws + NS_OFF;
    float* cnt     = ws + CNT_OFF;
    unsigned* done = (unsigned*)(ws + DONE_OFF);
    unsigned* sd   = (unsigned*)(ws + SD_OFF);
    unsigned* ct   = (unsigned*)(ws + CT_OFF);

    const int blk = blockIdx.x;
    const int tid = threadIdx.x;

    if (blk < NSCAT) {
        // ==================== scatter ====================
        const int b   = blk / BLKS_PER_B;
        const int sub = blk % BLKS_PER_B;
        const int wave = tid >> 6;
        const unsigned short lane = (unsigned short)(tid & 63);
        const unsigned f0 = (unsigned)sub * FWIN;
        const unsigned c0 = f0 >> 18;
        const unsigned p0 = f0 & (PP - 1);

        for (int i = tid; i < 8 * 1024; i += 512) ((float*)Rw)[i] = 0.f;
        __syncthreads();

        float*          wR = Rw[wave];
        unsigned short* wM = Mk[wave];

        const float* pb   = pred + (size_t)b * EPB;
        const int*   segb = seg + (size_t)b * PP + p0;

#define PREF(E0, SV, VV) do {                                     \
        SV = *(const int4*)(segb + (E0));                         \
        unsigned fk = f0 + (unsigned)(E0);                        \
        unsigned sp = fk / 21u;                                   \
        unsigned ch = fk - sp * 21u;                              \
        _Pragma("unroll")                                         \
        for (int k = 0; k < 4; ++k) {                             \
            VV[k] = pb[(ch << 18) + sp];                          \
            ch++;                                                 \
            bool c21 = (ch == 21u);                               \
            sp += c21 ? 1u : 0u;                                  \
            ch  = c21 ? 0u : ch;                                  \
        }                                                         \
    } while (0)

        int4 svN; float vN[4];
        PREF(tid * 4, svN, vN);

        for (int it = 0; it < FWIN / (512 * 4); ++it) {          // 16 iterations
            int4 sv = svN;
            float vA[4] = {vN[0], vN[1], vN[2], vN[3]};
            if (it + 1 < FWIN / (512 * 4)) {
                PREF(((it + 1) * 512 + tid) * 4, svN, vN);
            }
            int sA[4];
            #pragma unroll
            for (int k = 0; k < 4; ++k) {
                int s = (&sv.x)[k];
                sA[k] = ((unsigned)s < SPIX) ? s : DUMP;
            }
            #pragma unroll
            for (int i = 0; i < 3; ++i)
                #pragma unroll
                for (int j = i + 1; j < 4; ++j) {
                    bool e = (sA[j] == sA[i]) && (sA[i] != DUMP);
                    vA[i] += e ? vA[j] : 0.f;
                    sA[j]  = e ? DUMP  : sA[j];
                }
            #pragma unroll
            for (int k = 0; k < 4; ++k) wM[sA[k]] = lane;     // claims
            CLOBBER();
            unsigned short rd[4];
            #pragma unroll
            for (int k = 0; k < 4; ++k) rd[k] = wM[sA[k]];    // readback
            CLOBBER();
            float od[4];
            #pragma unroll
            for (int k = 0; k < 4; ++k) od[k] = wR[sA[k]];    // RMW read
            CLOBBER();
            bool lose1[4];
            #pragma unroll
            for (int k = 0; k < 4; ++k) {                     // winner write
                lose1[k] = (rd[k] != lane);
                wR[lose1[k] ? DUMP : sA[k]] = od[k] + vA[k];
            }
            CLOBBER();
            #pragma unroll
            for (int k = 0; k < 4; ++k) {                     // loser ds_add (~13%)
                if (lose1[k]) fatomic_add(&wR[sA[k]], vA[k]);
            }
        }
#undef PREF
        __syncthreads();

        float* Rbrow = Rbase + ((size_t)b * NCLS + c0) * SPIX;
        for (int i = tid; i < SPIX; i += 512) {
            float a = 0.f;
            #pragma unroll
            for (int w = 0; w < 8; ++w) a += Rw[w][i];
            if (a != 0.f) fatomic_add(&Rbrow[i], a);
        }
        __syncthreads();   // drain atomics (vmcnt before barrier)
        if (tid == 0)
            __hip_atomic_fetch_add(&done[b], 1u, __ATOMIC_RELEASE, __HIP_MEMORY_SCOPE_AGENT);

    } else if (blk < NSCAT + NSCAL) {
        // ==================== scalars ====================
        const int sb = blk - NSCAT;
        if (sb < 128) {
            const float4* W4 = (const float4*)W;
            const int n4 = (NB_IMG * SPIX * SPIX) / 4;
            float s = 0.f;
            for (int i = sb * 512 + tid; i < n4; i += 128 * 512) {
                float4 v = W4[i];
                s += v.x*v.x + v.y*v.y + v.z*v.z + v.w*v.w;
            }
            #pragma unroll
            for (int off = 32; off; off >>= 1) s += __shfl_xor(s, off);
            if ((tid & 63) == 0) fatomic_add(ns, s);
        } else {
            const int4* s4 = (const int4*)seg;
            const int n4 = (NB_IMG * PP) / 4;
            int c = 0;
            for (int i = (sb - 128) * 512 + tid; i < n4; i += 40 * 512) {
                int4 v = s4[i];
                c += ((unsigned)v.x < SPIX) + ((unsigned)v.y < SPIX) + ((unsigned)v.z < SPIX) + ((unsigned)v.w < SPIX);
            }
            float f = (float)c;
            #pragma unroll
            for (int off = 32; off; off >>= 1) f += __shfl_xor(f, off);
            if ((tid & 63) == 0) fatomic_add(cnt, f);
        }
        __syncthreads();   // drain atomics
        if (tid == 0)
            __hip_atomic_fetch_add(sd, 1u, __ATOMIC_RELEASE, __HIP_MEMORY_SCOPE_AGENT);

    } else {
        // ==================== trace ====================
        const int tb = blk - NSCAT - NSCAL;
        const int b  = tb / TXB;       // b=0 blocks first -> least waiting
        const int x  = tb % TXB;
        const int wave = tid >> 6;
        const int lane = tid & 63;

        // wait for batch b's scatter to complete
        if (tid == 0) {
            while (__hip_atomic_load(&done[b], __ATOMIC_ACQUIRE, __HIP_MEMORY_SCOPE_AGENT)
                   < (unsigned)BLKS_PER_B)
                __builtin_amdgcn_s_sleep(8);
        }
        __syncthreads();
        __builtin_amdgcn_fence(__ATOMIC_ACQUIRE, "agent");

        const float* Lb = L + (size_t)b * SPIX * SPIX;
        const float* Rg = Rbase + (size_t)b * NCLS * SPIX;

        const int s0 = (x * 8 + wave) * 2;
        const int s1 = s0 + 1;
        const bool v0 = s0 < SPIX, v1 = s1 < SPIX;
        const float4* L40 = (const float4*)(Lb + (size_t)(v0 ? s0 : (SPIX - 1)) * SPIX);
        const float4* L41 = (const float4*)(Lb + (size_t)(v1 ? s1 : (SPIX - 1)) * SPIX);

        float acc0[NCLS], acc1[NCLS];
        #pragma unroll
        for (int c = 0; c < NCLS; ++c) { acc0[c] = 0.f; acc1[c] = 0.f; }

        #pragma unroll
        for (int it = 0; it < 4; ++it) {
            int idx = it * 64 + lane;          // float4 index within row, 0..249
            if (idx < SPIX / 4) {
                float4 l0 = v0 ? L40[idx] : make_float4(0.f, 0.f, 0.f, 0.f);
                float4 l1 = v1 ? L41[idx] : make_float4(0.f, 0.f, 0.f, 0.f);
                #pragma unroll
                for (int c = 0; c < NCLS; ++c) {
                    float4 rr = ((const float4*)(Rg + c * SPIX))[idx];   // L1/L2-resident
                    acc0[c] += l0.x * rr.x + l0.y * rr.y + l0.z * rr.z + l0.w * rr.w;
                    acc1[c] += l1.x * rr.x + l1.y * rr.y + l1.z * rr.z + l1.w * rr.w;
                }
            }
        }

        float partial = 0.f;
        #pragma unroll
        for (int c = 0; c < NCLS; ++c) {
            if (v0) partial += Rg[c * SPIX + s0] * acc0[c];
            if (v1) partial += Rg[c * SPIX + s1] * acc1[c];
        }
        #pragma unroll
        for (int off = 32; off; off >>= 1) partial += __shfl_xor(partial, off);
        if (lane == 0) fatomic_add(&traces[b], partial);

        __syncthreads();   // drain trace atomics
        if (tid == 0) {
            unsigned old = __hip_atomic_fetch_add(ct, 1u, __ATOMIC_ACQ_REL, __HIP_MEMORY_SCOPE_AGENT);
            if (old == (unsigned)NTRC - 1u) {      // last trace block finalizes
                while (__hip_atomic_load(sd, __ATOMIC_ACQUIRE, __HIP_MEMORY_SCOPE_AGENT)
                       < (unsigned)NSCAL)
                    __builtin_amdgcn_s_sleep(8);
                float t = 0.f;
                #pragma unroll
                for (int i = 0; i < NB_IMG; ++i)
                    t += __hip_atomic_load(&traces[i], __ATOMIC_RELAXED, __HIP_MEMORY_SCOPE_AGENT);
                float nsv  = __hip_atomic_load(ns,  __ATOMIC_RELAXED, __HIP_MEMORY_SCOPE_AGENT);
                float cntv = __hip_atomic_load(cnt, __ATOMIC_RELAXED, __HIP_MEMORY_SCOPE_AGENT);
                float denom = cntv + 1e-16f;
                out[0] = (2.f / sqrtf(nsv)) * t / (denom * denom) / (float)NB_IMG;
            }
        }
    }
}

extern "C" void kernel_launch(void* const* d_in, const int* in_sizes, int n_in,
                              void* d_out, int out_size, void* d_ws, size_t ws_size,
                              hipStream_t stream) {
    const float* pred = (const float*)d_in[0];
    const float* Wc   = (const float*)d_in[1];
    const float* Lc   = (const float*)d_in[2];
    const int*   seg  = (const int*)d_in[3];
    float* ws = (float*)d_ws;
    float* out = (float*)d_out;

    (void)hipMemsetAsync(d_ws, 0, WS_FLOATS * sizeof(float), stream);

    fused_kernel<<<NBLKS, 512, 0, stream>>>(pred, seg, Wc, Lc, ws, out);
}

// Round 18
// 160.029 us; speedup vs baseline: 2.0343x; 1.7233x over previous
//
#include <hip/hip_runtime.h>
#include <hip/hip_bf16.h>

#define SPIX 1000
#define NCLS 21
#define PP (512*512)          // pixels per image, 2^18
#define NB_IMG 8
#define EPB (NCLS*PP)         // elements per batch in pred (= 21*2^18 f-values)

// scatter geometry: contiguous 32768-wide f-window per block; 2^15 | 2^18 so
// the class row c = f>>18 is CONSTANT within a block.
#define FWIN 32768
#define BLKS_PER_B (EPB / FWIN)   // 168
#define DUMP 1000                 // garbage accumulator slot (rows sized 1024)

#define TXB 63                    // trace x-blocks: 63*8waves*2rows = 1008 >= 1000
#define NTRC (TXB * NB_IMG)       // 504

// ws layout (floats)
#define R_OFF   0                      // [8][21][1000]
#define TR_OFF  (NB_IMG*NCLS*SPIX)     // [8]
#define NS_OFF  (TR_OFF + NB_IMG)      // [1] norm^2
#define CNT_OFF (NS_OFF + 1)           // [1] valid count
#define CTR_OFF (CNT_OFF + 1)          // [1] trace-block completion counter
#define WS_FLOATS (CTR_OFF + 1)

__device__ __forceinline__ void fatomic_add(float* p, float v) {
    unsafeAtomicAdd(p, v);   // native ds_add_f32 / global_atomic_add_f32
}

#define CLOBBER() asm volatile("" ::: "memory")

// Scatter + (on blockIdx.y==8) the ||W||^2 and valid-count reductions.
// R12 protocol (best measured: 109 us): per-phase clobbers, batched lgkm
// waits, u16 markers, winner-RMW + ds_add fallback for the ~13% losers.
__global__ __launch_bounds__(512, 8) void scatter_kernel(const float* __restrict__ pred,
                                                         const int* __restrict__ seg,
                                                         const float* __restrict__ W,
                                                         float* __restrict__ Rout,
                                                         float* __restrict__ ns,
                                                         float* __restrict__ cnt) {
    if (blockIdx.y == NB_IMG) {            // -------- scalars blocks --------
        if (blockIdx.x < 128) {
            const float4* W4 = (const float4*)W;
            const int n4 = (NB_IMG * SPIX * SPIX) / 4;
            float s = 0.f;
            for (int i = blockIdx.x * 512 + threadIdx.x; i < n4; i += 128 * 512) {
                float4 v = W4[i];
                s += v.x*v.x + v.y*v.y + v.z*v.z + v.w*v.w;
            }
            #pragma unroll
            for (int off = 32; off; off >>= 1) s += __shfl_xor(s, off);
            if ((threadIdx.x & 63) == 0) fatomic_add(ns, s);
        } else {
            const int4* s4 = (const int4*)seg;
            const int n4 = (NB_IMG * PP) / 4;
            int c = 0;
            for (int i = (blockIdx.x - 128) * 512 + threadIdx.x; i < n4; i += 40 * 512) {
                int4 v = s4[i];
                c += ((unsigned)v.x < SPIX) + ((unsigned)v.y < SPIX) + ((unsigned)v.z < SPIX) + ((unsigned)v.w < SPIX);
            }
            float f = (float)c;
            #pragma unroll
            for (int off = 32; off; off >>= 1) f += __shfl_xor(f, off);
            if ((threadIdx.x & 63) == 0) fatomic_add(cnt, f);
        }
        return;
    }
    // -------- scatter blocks --------
    __shared__ float          Rw[8][1024];   // wave-private accumulators, 32 KB
    __shared__ unsigned short Mk[8][1024];   // wave-private claim markers, 16 KB
    const int b    = blockIdx.y;
    const int tid  = threadIdx.x;
    const int wave = tid >> 6;
    const unsigned short lane = (unsigned short)(tid & 63);
    const unsigned f0 = (unsigned)blockIdx.x * FWIN;
    const unsigned c0 = f0 >> 18;            // constant class row for this block
    const unsigned p0 = f0 & (PP - 1);       // window start pixel (never wraps)

    for (int i = tid; i < 8 * 1024; i += 512) ((float*)Rw)[i] = 0.f;
    __syncthreads();

    float*          wR = Rw[wave];
    unsigned short* wM = Mk[wave];

    const float* pb   = pred + (size_t)b * EPB;
    const int*   segb = seg + (size_t)b * PP + p0;

    // issue-next-iteration loads (seg int4 + 4 pred gathers)
#define PREF(E0, SV, VV) do {                                     \
        SV = *(const int4*)(segb + (E0));                         \
        unsigned fk = f0 + (unsigned)(E0);                        \
        unsigned sp = fk / 21u;                                   \
        unsigned ch = fk - sp * 21u;                              \
        _Pragma("unroll")                                         \
        for (int k = 0; k < 4; ++k) {                             \
            VV[k] = pb[(ch << 18) + sp];                          \
            ch++;                                                 \
            bool c21 = (ch == 21u);                               \
            sp += c21 ? 1u : 0u;                                  \
            ch  = c21 ? 0u : ch;                                  \
        }                                                         \
    } while (0)

    int4 svN; float vN[4];
    PREF(tid * 4, svN, vN);                                  // prologue: it=0

    for (int it = 0; it < FWIN / (512 * 4); ++it) {          // 16 iterations
        int4 sv = svN;
        float vA[4] = {vN[0], vN[1], vN[2], vN[3]};
        if (it + 1 < FWIN / (512 * 4)) {
            PREF(((it + 1) * 512 + tid) * 4, svN, vN);       // in flight during protocol
        }
        int sA[4];
        #pragma unroll
        for (int k = 0; k < 4; ++k) {
            int s = (&sv.x)[k];
            sA[k] = ((unsigned)s < SPIX) ? s : DUMP;
        }
        // lane-local dedup: merge equal bins so a lane wins a bin at most once
        #pragma unroll
        for (int i = 0; i < 3; ++i)
            #pragma unroll
            for (int j = i + 1; j < 4; ++j) {
                bool e = (sA[j] == sA[i]) && (sA[i] != DUMP);
                vA[i] += e ? vA[j] : 0.f;
                sA[j]  = e ? DUMP  : sA[j];
            }
        // phase 1: claims (4 ds_write_b16, batched waits)
        #pragma unroll
        for (int k = 0; k < 4; ++k) wM[sA[k]] = lane;
        CLOBBER();
        // phase 2: claim readback (4 ds_read_u16)
        unsigned short rd[4];
        #pragma unroll
        for (int k = 0; k < 4; ++k) rd[k] = wM[sA[k]];
        CLOBBER();
        // phase 3: RMW reads (unconditional; losers read harmlessly)
        float od[4];
        #pragma unroll
        for (int k = 0; k < 4; ++k) od[k] = wR[sA[k]];
        CLOBBER();
        // phase 4: winner writes, branchless (losers write garbage to DUMP)
        bool lose1[4];
        #pragma unroll
        for (int k = 0; k < 4; ++k) {
            lose1[k] = (rd[k] != lane);
            wR[lose1[k] ? DUMP : sA[k]] = od[k] + vA[k];
        }
        CLOBBER();   // order winner writes before fallbacks (in-order DS FIFO)
        // phase 5: loser fallback on the atomic pipe (~13% of lanes)
        #pragma unroll
        for (int k = 0; k < 4; ++k) {
            if (lose1[k]) fatomic_add(&wR[sA[k]], vA[k]);
        }
    }
#undef PREF
    __syncthreads();

    // merge 8 wave copies, one global atomic per bin
    float* Rb = Rout + (size_t)b * NCLS * SPIX + (size_t)c0 * SPIX;
    for (int i = tid; i < SPIX; i += 512) {
        float a = 0.f;
        #pragma unroll
        for (int w = 0; w < 8; ++w) a += Rw[w][i];
        if (a != 0.f) fatomic_add(&Rb[i], a);
    }
}

// trace[b] = sum_{s,t} L[b,s,t] * sum_c R[b,c,s]*R[b,c,t].
// LDS-free: R (672 KB total) is L2-resident; reading it directly instead of
// staging 84 KB/block lifts occupancy from 1 block/CU to many and lets the
// L stream run at HBM rate. 63 blocks x 8 waves x 2 rows per batch.
__global__ __launch_bounds__(512) void trace_kernel(const float* __restrict__ L,
                                                    const float* __restrict__ R,
                                                    float* __restrict__ traces,
                                                    const float* __restrict__ ns,
                                                    const float* __restrict__ cnt,
                                                    unsigned* __restrict__ ctr,
                                                    float* __restrict__ out) {
    const int b = blockIdx.y;
    const int wave = threadIdx.x >> 6;
    const int lane = threadIdx.x & 63;
    const float* Lb = L + (size_t)b * SPIX * SPIX;
    const float* Rg = R + (size_t)b * NCLS * SPIX;

    const int s0 = (blockIdx.x * 8 + wave) * 2;
    const int s1 = s0 + 1;
    const bool v0 = s0 < SPIX, v1 = s1 < SPIX;
    const float4* L40 = (const float4*)(Lb + (size_t)(v0 ? s0 : (SPIX - 1)) * SPIX);
    const float4* L41 = (const float4*)(Lb + (size_t)(v1 ? s1 : (SPIX - 1)) * SPIX);

    float acc0[NCLS], acc1[NCLS];
    #pragma unroll
    for (int c = 0; c < NCLS; ++c) { acc0[c] = 0.f; acc1[c] = 0.f; }

    #pragma unroll
    for (int it = 0; it < 4; ++it) {
        int idx = it * 64 + lane;          // float4 index within row, 0..249
        if (idx < SPIX / 4) {
            float4 l0 = v0 ? L40[idx] : make_float4(0.f, 0.f, 0.f, 0.f);
            float4 l1 = v1 ? L41[idx] : make_float4(0.f, 0.f, 0.f, 0.f);
            #pragma unroll
            for (int c = 0; c < NCLS; ++c) {
                float4 rr = ((const float4*)(Rg + c * SPIX))[idx];   // L2-resident
                acc0[c] += l0.x * rr.x + l0.y * rr.y + l0.z * rr.z + l0.w * rr.w;
                acc1[c] += l1.x * rr.x + l1.y * rr.y + l1.z * rr.z + l1.w * rr.w;
            }
        }
    }

    float partial = 0.f;
    #pragma unroll
    for (int c = 0; c < NCLS; ++c) {
        if (v0) partial += Rg[c * SPIX + s0] * acc0[c];   // wave-uniform -> s_loads
        if (v1) partial += Rg[c * SPIX + s1] * acc1[c];
    }
    #pragma unroll
    for (int off = 32; off; off >>= 1) partial += __shfl_xor(partial, off);
    if (lane == 0) fatomic_add(&traces[b], partial);

    __syncthreads();   // drain this block's atomics
    if (threadIdx.x == 0) {
        __threadfence();
        unsigned old = atomicAdd(ctr, 1u);
        if (old == (unsigned)(TXB * NB_IMG) - 1u) {   // last block finalizes
            __threadfence();
            float t = 0.f;
            #pragma unroll
            for (int i = 0; i < NB_IMG; ++i)
                t += __hip_atomic_load(&traces[i], __ATOMIC_RELAXED, __HIP_MEMORY_SCOPE_AGENT);
            float denom = cnt[0] + 1e-16f;
            out[0] = (2.f / sqrtf(ns[0])) * t / (denom * denom) / (float)NB_IMG;
        }
    }
}

extern "C" void kernel_launch(void* const* d_in, const int* in_sizes, int n_in,
                              void* d_out, int out_size, void* d_ws, size_t ws_size,
                              hipStream_t stream) {
    const float* pred = (const float*)d_in[0];
    const float* Wc   = (const float*)d_in[1];
    const float* Lc   = (const float*)d_in[2];
    const int*   seg  = (const int*)d_in[3];
    float* ws = (float*)d_ws;
    float* out = (float*)d_out;

    (void)hipMemsetAsync(d_ws, 0, WS_FLOATS * sizeof(float), stream);

    scatter_kernel<<<dim3(BLKS_PER_B, NB_IMG + 1), 512, 0, stream>>>(
        pred, seg, Wc, ws + R_OFF, ws + NS_OFF, ws + CNT_OFF);

    trace_kernel<<<dim3(TXB, NB_IMG), 512, 0, stream>>>(
        Lc, ws + R_OFF, ws + TR_OFF, ws + NS_OFF, ws + CNT_OFF,
        (unsigned*)(ws + CTR_OFF), out);
}

// Round 19
// 139.534 us; speedup vs baseline: 2.3332x; 1.1469x over previous
//
#include <hip/hip_runtime.h>
#include <hip/hip_bf16.h>

#define SPIX 1000
#define NCLS 21
#define PP (512*512)          // pixels per image, 2^18
#define NB_IMG 8
#define EPB (NCLS*PP)         // elements per batch in pred (= 21*2^18 f-values)

// scatter geometry: contiguous 32768-wide f-window per block; 2^15 | 2^18 so
// the class row c = f>>18 is CONSTANT within a block.
#define FWIN 32768
#define BLKS_PER_B (EPB / FWIN)   // 168
#define DUMP 1000                 // garbage accumulator slot (rows sized 1024)

// ws layout (floats)
#define R_OFF   0                      // [8][21][1000]
#define TR_OFF  (NB_IMG*NCLS*SPIX)     // [8]
#define NS_OFF  (TR_OFF + NB_IMG)      // [1] norm^2
#define CNT_OFF (NS_OFF + 1)           // [1] valid count
#define CTR_OFF (CNT_OFF + 1)          // [1] trace-block completion counter
#define WS_FLOATS (CTR_OFF + 1)

__device__ __forceinline__ void fatomic_add(float* p, float v) {
    unsafeAtomicAdd(p, v);   // native ds_add_f32 / global_atomic_add_f32
}

#define CLOBBER() asm volatile("" ::: "memory")

// Scatter + (on blockIdx.y==8) the ||W||^2 and valid-count reductions.
// R12 protocol (per-phase clobbers, batched lgkm waits, u16 markers) + an
// EXEC-MASKED round-2 rescue under the clobber regime: ~13% of lanes re-claim,
// converting ~28/30 per-iter atomic-pipe fallbacks (3.6 cyc/lane serial) into
// masked banked ops. R7/R8 rescue failures were volatile-regime artifacts.
__global__ __launch_bounds__(512, 8) void scatter_kernel(const float* __restrict__ pred,
                                                         const int* __restrict__ seg,
                                                         const float* __restrict__ W,
                                                         float* __restrict__ Rout,
                                                         float* __restrict__ ns,
                                                         float* __restrict__ cnt) {
    if (blockIdx.y == NB_IMG) {            // -------- scalars blocks --------
        if (blockIdx.x < 128) {
            const float4* W4 = (const float4*)W;
            const int n4 = (NB_IMG * SPIX * SPIX) / 4;
            float s = 0.f;
            for (int i = blockIdx.x * 512 + threadIdx.x; i < n4; i += 128 * 512) {
                float4 v = W4[i];
                s += v.x*v.x + v.y*v.y + v.z*v.z + v.w*v.w;
            }
            #pragma unroll
            for (int off = 32; off; off >>= 1) s += __shfl_xor(s, off);
            if ((threadIdx.x & 63) == 0) fatomic_add(ns, s);
        } else {
            const int4* s4 = (const int4*)seg;
            const int n4 = (NB_IMG * PP) / 4;
            int c = 0;
            for (int i = (blockIdx.x - 128) * 512 + threadIdx.x; i < n4; i += 40 * 512) {
                int4 v = s4[i];
                c += ((unsigned)v.x < SPIX) + ((unsigned)v.y < SPIX) + ((unsigned)v.z < SPIX) + ((unsigned)v.w < SPIX);
            }
            float f = (float)c;
            #pragma unroll
            for (int off = 32; off; off >>= 1) f += __shfl_xor(f, off);
            if ((threadIdx.x & 63) == 0) fatomic_add(cnt, f);
        }
        return;
    }
    // -------- scatter blocks --------
    __shared__ float          Rw[8][1024];   // wave-private accumulators, 32 KB
    __shared__ unsigned short Mk[8][1024];   // wave-private claim markers, 16 KB
    const int b    = blockIdx.y;
    const int tid  = threadIdx.x;
    const int wave = tid >> 6;
    const unsigned short lane = (unsigned short)(tid & 63);
    const unsigned f0 = (unsigned)blockIdx.x * FWIN;
    const unsigned c0 = f0 >> 18;            // constant class row for this block
    const unsigned p0 = f0 & (PP - 1);       // window start pixel (never wraps)

    for (int i = tid; i < 8 * 1024; i += 512) ((float*)Rw)[i] = 0.f;
    __syncthreads();

    float*          wR = Rw[wave];
    unsigned short* wM = Mk[wave];

    const float* pb   = pred + (size_t)b * EPB;
    const int*   segb = seg + (size_t)b * PP + p0;

    // issue-next-iteration loads (seg int4 + 4 pred gathers)
#define PREF(E0, SV, VV) do {                                     \
        SV = *(const int4*)(segb + (E0));                         \
        unsigned fk = f0 + (unsigned)(E0);                        \
        unsigned sp = fk / 21u;                                   \
        unsigned ch = fk - sp * 21u;                              \
        _Pragma("unroll")                                         \
        for (int k = 0; k < 4; ++k) {                             \
            VV[k] = pb[(ch << 18) + sp];                          \
            ch++;                                                 \
            bool c21 = (ch == 21u);                               \
            sp += c21 ? 1u : 0u;                                  \
            ch  = c21 ? 0u : ch;                                  \
        }                                                         \
    } while (0)

    int4 svN; float vN[4];
    PREF(tid * 4, svN, vN);                                  // prologue: it=0

    for (int it = 0; it < FWIN / (512 * 4); ++it) {          // 16 iterations
        int4 sv = svN;
        float vA[4] = {vN[0], vN[1], vN[2], vN[3]};
        if (it + 1 < FWIN / (512 * 4)) {
            PREF(((it + 1) * 512 + tid) * 4, svN, vN);       // in flight during protocol
        }
        int sA[4];
        #pragma unroll
        for (int k = 0; k < 4; ++k) {
            int s = (&sv.x)[k];
            sA[k] = ((unsigned)s < SPIX) ? s : DUMP;
        }
        // lane-local dedup: merge equal bins so a lane wins a bin at most once
        #pragma unroll
        for (int i = 0; i < 3; ++i)
            #pragma unroll
            for (int j = i + 1; j < 4; ++j) {
                bool e = (sA[j] == sA[i]) && (sA[i] != DUMP);
                vA[i] += e ? vA[j] : 0.f;
                sA[j]  = e ? DUMP  : sA[j];
            }
        // ---- round 1 ----
        #pragma unroll
        for (int k = 0; k < 4; ++k) wM[sA[k]] = lane;        // claims
        CLOBBER();
        unsigned short rd[4];
        #pragma unroll
        for (int k = 0; k < 4; ++k) rd[k] = wM[sA[k]];       // readback
        CLOBBER();
        float od[4];
        #pragma unroll
        for (int k = 0; k < 4; ++k) od[k] = wR[sA[k]];       // RMW read
        CLOBBER();
        bool lose1[4];
        #pragma unroll
        for (int k = 0; k < 4; ++k) {                        // winner write
            lose1[k] = (rd[k] != lane);
            wR[lose1[k] ? DUMP : sA[k]] = od[k] + vA[k];
        }
        CLOBBER();
        // ---- round 2: exec-masked rescue (~13% of lanes active) ----
        #pragma unroll
        for (int k = 0; k < 4; ++k) { if (lose1[k]) wM[sA[k]] = lane; }
        CLOBBER();
        unsigned short rd2[4];
        #pragma unroll
        for (int k = 0; k < 4; ++k) rd2[k] = lose1[k] ? wM[sA[k]] : (unsigned short)0xffffu;
        CLOBBER();
        float od2[4];
        #pragma unroll
        for (int k = 0; k < 4; ++k) { if (lose1[k]) od2[k] = wR[sA[k]]; }
        CLOBBER();
        #pragma unroll
        for (int k = 0; k < 4; ++k) {
            if (rd2[k] == lane) wR[sA[k]] = od2[k] + vA[k];  // round-2 winners
        }
        CLOBBER();
        // ---- round 3: double-losers on the atomic pipe (~1%) ----
        #pragma unroll
        for (int k = 0; k < 4; ++k) {
            if (lose1[k] && rd2[k] != lane) fatomic_add(&wR[sA[k]], vA[k]);
        }
    }
#undef PREF
    __syncthreads();

    // merge 8 wave copies, one global atomic per bin
    float* Rb = Rout + (size_t)b * NCLS * SPIX + (size_t)c0 * SPIX;
    for (int i = tid; i < SPIX; i += 512) {
        float a = 0.f;
        #pragma unroll
        for (int w = 0; w < 8; ++w) a += Rw[w][i];
        if (a != 0.f) fatomic_add(&Rb[i], a);
    }
}

// trace[b] = sum_{s,t} L[b,s,t] * sum_c R[b,c,s]*R[b,c,t]; last block finalizes.
// R12 form: LDS-staged R (faster than L2 re-reads — R18 measured), 4 rows/wave.
__global__ __launch_bounds__(512) void trace_kernel(const float* __restrict__ L,
                                                    const float* __restrict__ R,
                                                    float* __restrict__ traces,
                                                    const float* __restrict__ ns,
                                                    const float* __restrict__ cnt,
                                                    unsigned* __restrict__ ctr,
                                                    float* __restrict__ out) {
    __shared__ float Rl[NCLS * SPIX];   // 84 KB
    const int b = blockIdx.y;
    const float* Rb = R + (size_t)b * NCLS * SPIX;
    for (int i = threadIdx.x; i < NCLS * SPIX; i += 512) Rl[i] = Rb[i];
    __syncthreads();

    const int wave = threadIdx.x >> 6;
    const int lane = threadIdx.x & 63;
    const float* Lb = L + (size_t)b * SPIX * SPIX;

    const int s0 = (blockIdx.x * 8 + wave) * 4;   // 32 blocks * 8 waves * 4 rows = 1024
    bool val[4];
    const float4* Lr[4];
    #pragma unroll
    for (int r = 0; r < 4; ++r) {
        int sr = s0 + r;
        val[r] = sr < SPIX;
        Lr[r] = (const float4*)(Lb + (size_t)(val[r] ? sr : (SPIX - 1)) * SPIX);
    }

    float acc[4][NCLS];
    #pragma unroll
    for (int r = 0; r < 4; ++r)
        #pragma unroll
        for (int c = 0; c < NCLS; ++c) acc[r][c] = 0.f;

    #pragma unroll
    for (int it = 0; it < 4; ++it) {
        int idx = it * 64 + lane;          // float4 index within row, 0..249
        if (idx < SPIX / 4) {
            float4 l[4];
            #pragma unroll
            for (int r = 0; r < 4; ++r)
                l[r] = val[r] ? Lr[r][idx] : make_float4(0.f, 0.f, 0.f, 0.f);
            #pragma unroll
            for (int c = 0; c < NCLS; ++c) {
                float4 rr = *(const float4*)&Rl[c * SPIX + idx * 4];
                #pragma unroll
                for (int r = 0; r < 4; ++r)
                    acc[r][c] += l[r].x * rr.x + l[r].y * rr.y + l[r].z * rr.z + l[r].w * rr.w;
            }
        }
    }

    float partial = 0.f;
    #pragma unroll
    for (int c = 0; c < NCLS; ++c)
        #pragma unroll
        for (int r = 0; r < 4; ++r)
            if (val[r]) partial += Rl[c * SPIX + s0 + r] * acc[r][c];

    #pragma unroll
    for (int off = 32; off; off >>= 1) partial += __shfl_xor(partial, off);
    if (lane == 0) fatomic_add(&traces[b], partial);

    __syncthreads();
    if (threadIdx.x == 0) {
        __threadfence();
        unsigned old = atomicAdd(ctr, 1u);
        if (old == 32u * NB_IMG - 1u) {    // last block finalizes
            __threadfence();
            float t = 0.f;
            #pragma unroll
            for (int i = 0; i < NB_IMG; ++i)
                t += __hip_atomic_load(&traces[i], __ATOMIC_RELAXED, __HIP_MEMORY_SCOPE_AGENT);
            float denom = cnt[0] + 1e-16f;
            out[0] = (2.f / sqrtf(ns[0])) * t / (denom * denom) / (float)NB_IMG;
        }
    }
}

extern "C" void kernel_launch(void* const* d_in, const int* in_sizes, int n_in,
                              void* d_out, int out_size, void* d_ws, size_t ws_size,
                              hipStream_t stream) {
    const float* pred = (const float*)d_in[0];
    const float* Wc   = (const float*)d_in[1];
    const float* Lc   = (const float*)d_in[2];
    const int*   seg  = (const int*)d_in[3];
    float* ws = (float*)d_ws;
    float* out = (float*)d_out;

    (void)hipMemsetAsync(d_ws, 0, WS_FLOATS * sizeof(float), stream);

    scatter_kernel<<<dim3(BLKS_PER_B, NB_IMG + 1), 512, 0, stream>>>(
        pred, seg, Wc, ws + R_OFF, ws + NS_OFF, ws + CNT_OFF);

    trace_kernel<<<dim3(32, NB_IMG), 512, 0, stream>>>(
        Lc, ws + R_OFF, ws + TR_OFF, ws + NS_OFF, ws + CNT_OFF,
        (unsigned*)(ws + CTR_OFF), out);
}

// Round 20
// 137.283 us; speedup vs baseline: 2.3714x; 1.0164x over previous
//
#include <hip/hip_runtime.h>
#include <hip/hip_bf16.h>

#define SPIX 1000
#define NCLS 21
#define PP (512*512)          // pixels per image, 2^18
#define NB_IMG 8
#define EPB (NCLS*PP)         // elements per batch in pred (= 21*2^18 f-values)

// scatter geometry: contiguous 32768-wide f-window per block; 2^15 | 2^18 so
// the class row c = f>>18 is CONSTANT within a block.
#define FWIN 32768
#define BLKS_PER_B (EPB / FWIN)   // 168
#define DUMP 1000                 // garbage accumulator slot (rows sized 1024)

// ws layout (floats)
#define R_OFF   0                      // [8][21][1000]
#define TR_OFF  (NB_IMG*NCLS*SPIX)     // [8]
#define NS_OFF  (TR_OFF + NB_IMG)      // [1] norm^2
#define CNT_OFF (NS_OFF + 1)           // [1] valid count
#define CTR_OFF (CNT_OFF + 1)          // [1] trace-block completion counter
#define WS_FLOATS (CTR_OFF + 1)

__device__ __forceinline__ void fatomic_add(float* p, float v) {
    unsafeAtomicAdd(p, v);   // native ds_add_f32 / global_atomic_add_f32
}

#define CLOBBER() asm volatile("" ::: "memory")

// Scatter + (on blockIdx.y==8) the ||W||^2 and valid-count reductions.
// EXACT R12 protocol (best measured: 109 us across 8 variants): per-phase
// clobbers, batched lgkm waits, u16 markers, winner-RMW + ds_add fallback.
__global__ __launch_bounds__(512, 8) void scatter_kernel(const float* __restrict__ pred,
                                                         const int* __restrict__ seg,
                                                         const float* __restrict__ W,
                                                         float* __restrict__ Rout,
                                                         float* __restrict__ ns,
                                                         float* __restrict__ cnt) {
    if (blockIdx.y == NB_IMG) {            // -------- scalars blocks --------
        if (blockIdx.x < 128) {
            const float4* W4 = (const float4*)W;
            const int n4 = (NB_IMG * SPIX * SPIX) / 4;
            float s = 0.f;
            for (int i = blockIdx.x * 512 + threadIdx.x; i < n4; i += 128 * 512) {
                float4 v = W4[i];
                s += v.x*v.x + v.y*v.y + v.z*v.z + v.w*v.w;
            }
            #pragma unroll
            for (int off = 32; off; off >>= 1) s += __shfl_xor(s, off);
            if ((threadIdx.x & 63) == 0) fatomic_add(ns, s);
        } else {
            const int4* s4 = (const int4*)seg;
            const int n4 = (NB_IMG * PP) / 4;
            int c = 0;
            for (int i = (blockIdx.x - 128) * 512 + threadIdx.x; i < n4; i += 40 * 512) {
                int4 v = s4[i];
                c += ((unsigned)v.x < SPIX) + ((unsigned)v.y < SPIX) + ((unsigned)v.z < SPIX) + ((unsigned)v.w < SPIX);
            }
            float f = (float)c;
            #pragma unroll
            for (int off = 32; off; off >>= 1) f += __shfl_xor(f, off);
            if ((threadIdx.x & 63) == 0) fatomic_add(cnt, f);
        }
        return;
    }
    // -------- scatter blocks --------
    __shared__ float          Rw[8][1024];   // wave-private accumulators, 32 KB
    __shared__ unsigned short Mk[8][1024];   // wave-private claim markers, 16 KB
    const int b    = blockIdx.y;
    const int tid  = threadIdx.x;
    const int wave = tid >> 6;
    const unsigned short lane = (unsigned short)(tid & 63);
    const unsigned f0 = (unsigned)blockIdx.x * FWIN;
    const unsigned c0 = f0 >> 18;            // constant class row for this block
    const unsigned p0 = f0 & (PP - 1);       // window start pixel (never wraps)

    for (int i = tid; i < 8 * 1024; i += 512) ((float*)Rw)[i] = 0.f;
    __syncthreads();

    float*          wR = Rw[wave];
    unsigned short* wM = Mk[wave];

    const float* pb   = pred + (size_t)b * EPB;
    const int*   segb = seg + (size_t)b * PP + p0;

    // issue-next-iteration loads (seg int4 + 4 pred gathers)
#define PREF(E0, SV, VV) do {                                     \
        SV = *(const int4*)(segb + (E0));                         \
        unsigned fk = f0 + (unsigned)(E0);                        \
        unsigned sp = fk / 21u;                                   \
        unsigned ch = fk - sp * 21u;                              \
        _Pragma("unroll")                                         \
        for (int k = 0; k < 4; ++k) {                             \
            VV[k] = pb[(ch << 18) + sp];                          \
            ch++;                                                 \
            bool c21 = (ch == 21u);                               \
            sp += c21 ? 1u : 0u;                                  \
            ch  = c21 ? 0u : ch;                                  \
        }                                                         \
    } while (0)

    int4 svN; float vN[4];
    PREF(tid * 4, svN, vN);                                  // prologue: it=0

    for (int it = 0; it < FWIN / (512 * 4); ++it) {          // 16 iterations
        int4 sv = svN;
        float vA[4] = {vN[0], vN[1], vN[2], vN[3]};
        if (it + 1 < FWIN / (512 * 4)) {
            PREF(((it + 1) * 512 + tid) * 4, svN, vN);       // in flight during protocol
        }
        int sA[4];
        #pragma unroll
        for (int k = 0; k < 4; ++k) {
            int s = (&sv.x)[k];
            sA[k] = ((unsigned)s < SPIX) ? s : DUMP;
        }
        // lane-local dedup: merge equal bins so a lane wins a bin at most once
        #pragma unroll
        for (int i = 0; i < 3; ++i)
            #pragma unroll
            for (int j = i + 1; j < 4; ++j) {
                bool e = (sA[j] == sA[i]) && (sA[i] != DUMP);
                vA[i] += e ? vA[j] : 0.f;
                sA[j]  = e ? DUMP  : sA[j];
            }
        // phase 1: claims (4 ds_write_b16, batched waits)
        #pragma unroll
        for (int k = 0; k < 4; ++k) wM[sA[k]] = lane;
        CLOBBER();
        // phase 2: claim readback (4 ds_read_u16)
        unsigned short rd[4];
        #pragma unroll
        for (int k = 0; k < 4; ++k) rd[k] = wM[sA[k]];
        CLOBBER();
        // phase 3: RMW reads (unconditional; losers read harmlessly)
        float od[4];
        #pragma unroll
        for (int k = 0; k < 4; ++k) od[k] = wR[sA[k]];
        CLOBBER();
        // phase 4: winner writes, branchless (losers write garbage to DUMP)
        bool lose1[4];
        #pragma unroll
        for (int k = 0; k < 4; ++k) {
            lose1[k] = (rd[k] != lane);
            wR[lose1[k] ? DUMP : sA[k]] = od[k] + vA[k];
        }
        CLOBBER();   // order winner writes before fallbacks (in-order DS FIFO)
        // phase 5: loser fallback on the atomic pipe (~13% of lanes)
        #pragma unroll
        for (int k = 0; k < 4; ++k) {
            if (lose1[k]) fatomic_add(&wR[sA[k]], vA[k]);
        }
    }
#undef PREF
    __syncthreads();

    // merge 8 wave copies, one global atomic per bin
    float* Rb = Rout + (size_t)b * NCLS * SPIX + (size_t)c0 * SPIX;
    for (int i = tid; i < SPIX; i += 512) {
        float a = 0.f;
        #pragma unroll
        for (int w = 0; w < 8; ++w) a += Rw[w][i];
        if (a != 0.f) fatomic_add(&Rb[i], a);
    }
}

// trace[b] = sum_{s,t} L[b,s,t] * sum_c R[b,c,s]*R[b,c,t]; last block finalizes.
// 8 L-rows per wave x half the idx range (grid x = rowgroup*2 + half):
// same FLOPs/L-traffic as 4-rows/full-range, but each ds_read_b128 of R now
// feeds 8 rows -> LDS-read serialization (the 13us bottleneck) halves.
__global__ __launch_bounds__(512) void trace_kernel(const float* __restrict__ L,
                                                    const float* __restrict__ R,
                                                    float* __restrict__ traces,
                                                    const float* __restrict__ ns,
                                                    const float* __restrict__ cnt,
                                                    unsigned* __restrict__ ctr,
                                                    float* __restrict__ out) {
    __shared__ float Rl[NCLS * SPIX];   // 84 KB
    const int b = blockIdx.y;
    const float* Rb = R + (size_t)b * NCLS * SPIX;
    for (int i = threadIdx.x; i < NCLS * SPIX; i += 512) Rl[i] = Rb[i];
    __syncthreads();

    const int wave = threadIdx.x >> 6;
    const int lane = threadIdx.x & 63;
    const int rg = blockIdx.x >> 1;        // row-group 0..15
    const int ih = blockIdx.x & 1;         // idx half 0..1
    const float* Lb = L + (size_t)b * SPIX * SPIX;

    const int s0 = rg * 64 + wave * 8;     // 8 rows per wave (16*64 = 1024 >= 1000)
    bool val[8];
    const float4* Lr[8];
    #pragma unroll
    for (int r = 0; r < 8; ++r) {
        int sr = s0 + r;
        val[r] = sr < SPIX;
        Lr[r] = (const float4*)(Lb + (size_t)(val[r] ? sr : (SPIX - 1)) * SPIX);
    }

    float acc[8][NCLS];
    #pragma unroll
    for (int r = 0; r < 8; ++r)
        #pragma unroll
        for (int c = 0; c < NCLS; ++c) acc[r][c] = 0.f;

    #pragma unroll
    for (int it = 0; it < 2; ++it) {
        int j = it * 64 + lane;            // 0..127 over the 125-wide half
        if (j < 125) {
            int idx = ih * 125 + j;        // float4 index 0..249
            float4 l[8];
            #pragma unroll
            for (int r = 0; r < 8; ++r)
                l[r] = val[r] ? Lr[r][idx] : make_float4(0.f, 0.f, 0.f, 0.f);
            #pragma unroll
            for (int c = 0; c < NCLS; ++c) {
                float4 rr = *(const float4*)&Rl[c * SPIX + idx * 4];
                #pragma unroll
                for (int r = 0; r < 8; ++r)
                    acc[r][c] += l[r].x * rr.x + l[r].y * rr.y + l[r].z * rr.z + l[r].w * rr.w;
            }
        }
    }

    float partial = 0.f;
    #pragma unroll
    for (int c = 0; c < NCLS; ++c)
        #pragma unroll
        for (int r = 0; r < 8; ++r)
            if (val[r]) partial += Rl[c * SPIX + s0 + r] * acc[r][c];

    #pragma unroll
    for (int off = 32; off; off >>= 1) partial += __shfl_xor(partial, off);
    if (lane == 0) fatomic_add(&traces[b], partial);

    __syncthreads();
    if (threadIdx.x == 0) {
        __threadfence();
        unsigned old = atomicAdd(ctr, 1u);
        if (old == 32u * NB_IMG - 1u) {    // last block finalizes
            __threadfence();
            float t = 0.f;
            #pragma unroll
            for (int i = 0; i < NB_IMG; ++i)
                t += __hip_atomic_load(&traces[i], __ATOMIC_RELAXED, __HIP_MEMORY_SCOPE_AGENT);
            float denom = cnt[0] + 1e-16f;
            out[0] = (2.f / sqrtf(ns[0])) * t / (denom * denom) / (float)NB_IMG;
        }
    }
}

extern "C" void kernel_launch(void* const* d_in, const int* in_sizes, int n_in,
                              void* d_out, int out_size, void* d_ws, size_t ws_size,
                              hipStream_t stream) {
    const float* pred = (const float*)d_in[0];
    const float* Wc   = (const float*)d_in[1];
    const float* Lc   = (const float*)d_in[2];
    const int*   seg  = (const int*)d_in[3];
    float* ws = (float*)d_ws;
    float* out = (float*)d_out;

    (void)hipMemsetAsync(d_ws, 0, WS_FLOATS * sizeof(float), stream);

    scatter_kernel<<<dim3(BLKS_PER_B, NB_IMG + 1), 512, 0, stream>>>(
        pred, seg, Wc, ws + R_OFF, ws + NS_OFF, ws + CNT_OFF);

    trace_kernel<<<dim3(32, NB_IMG), 512, 0, stream>>>(
        Lc, ws + R_OFF, ws + TR_OFF, ws + NS_OFF, ws + CNT_OFF,
        (unsigned*)(ws + CTR_OFF), out);
}